// Round 4
// baseline (4794.860 us; speedup 1.0000x reference)
//
#include <hip/hip_runtime.h>
#include <hip/hip_bf16.h>

typedef unsigned short u16;
typedef short bf16x8 __attribute__((ext_vector_type(8)));
typedef float f32x4 __attribute__((ext_vector_type(4)));

__device__ __forceinline__ float ldbf(const u16* p) {
    __hip_bfloat16 h = *(const __hip_bfloat16*)p;
    return __bfloat162float(h);
}
__device__ __forceinline__ void stbf(u16* p, float f) {
    *(__hip_bfloat16*)p = __float2bfloat16(f);
}
__device__ __forceinline__ float sigm(float x) {
    return 1.0f / (1.0f + __expf(-x));
}

// ---------------------------------------------------------------------------
// f32 -> bf16 conversion (for w_hh)
// ---------------------------------------------------------------------------
__global__ __launch_bounds__(256) void cvt_bf16(const float* __restrict__ in,
                                                u16* __restrict__ out, int n) {
    int i = blockIdx.x * 256 + threadIdx.x;
    if (i < n) stbf(out + i, in[i]);
}

// ---------------------------------------------------------------------------
// Upsample conv: out[2l+s, b, c] = relu(bias[oc] + sum_k w[oc,k]*in[l+k-3, b, oc>>shift])
// oc = c + 512*s. in: [Lin][128][Cin], Cin = 1024>>shift (f32 or bf16).
// out: [2*Lin][128][512] bf16.
// ---------------------------------------------------------------------------
template <bool INF32>
__global__ __launch_bounds__(256) void upsample(const void* __restrict__ in_,
                                                const float* __restrict__ w,
                                                const float* __restrict__ bias_,
                                                u16* __restrict__ out,
                                                int Lin, int shift) {
    const int Cin = 1024 >> shift;
    const int total = 2 * Lin * 128 * 512;
    int idx = blockIdx.x * 256 + threadIdx.x;
    if (idx >= total) return;
    const int c  = idx & 511;
    const int bb = (idx >> 9) & 127;
    const int tp = idx >> 16;          // t = 2l + s
    const int s  = tp & 1;
    const int l  = tp >> 1;
    const int oc = c + (s << 9);
    const int ch = oc >> shift;
    float acc = bias_[oc];
    #pragma unroll
    for (int k = 0; k < 7; ++k) {
        int li = l + k - 3;
        if (li >= 0 && li < Lin) {
            size_t off = ((size_t)li * 128 + bb) * Cin + ch;
            float v = INF32 ? ((const float*)in_)[off] : ldbf((const u16*)in_ + off);
            acc += w[oc * 7 + k] * v;
        }
    }
    stbf(out + idx, fmaxf(acc, 0.0f));
}

// ---------------------------------------------------------------------------
// gates_x GEMM (MFMA): gates[r, n] = sum_k A[r,k] * w_ih[n,k] + b_ih[n] + b_hh[n]
//   A[r,k<512]  = x[r*512+k]                  (f32)
//   A[r,k>=512] = z2[65536 + r*512 + (k-512)] (bf16)
// M=65408 (511 tiles of 128), N=2048 (16 tiles), K=1024 (32 iters of BK=32).
// ---------------------------------------------------------------------------
__global__ __launch_bounds__(256) void gemm_gates(const float* __restrict__ x,
                                                  const u16* __restrict__ z2,
                                                  const float* __restrict__ wih,
                                                  const float* __restrict__ bih,
                                                  const float* __restrict__ bhh,
                                                  u16* __restrict__ gates) {
    __shared__ __align__(16) u16 smA[128 * 32];
    __shared__ __align__(16) u16 smB[128 * 32];
    const int tid  = threadIdx.x;
    const int lane = tid & 63;
    const int wave = tid >> 6;
    const int wm = wave >> 1, wn = wave & 1;
    const size_t mbase = (size_t)blockIdx.x * 128;
    const size_t nbase = (size_t)blockIdx.y * 128;

    f32x4 acc[4][4] = {};

    const int srow = tid >> 1;            // staging row 0..127
    const int scol = (tid & 1) * 16;      // staging col 0 or 16

    for (int kt = 0; kt < 32; ++kt) {
        const int kb = kt * 32;
        // stage A tile [128][32]
        if (kb < 512) {
            const float* src = x + (mbase + srow) * 512 + kb + scol;
            alignas(16) u16 tmp[16];
            #pragma unroll
            for (int q = 0; q < 16; ++q) stbf(&tmp[q], src[q]);
            *(int4*)&smA[srow * 32 + scol]     = *(const int4*)&tmp[0];
            *(int4*)&smA[srow * 32 + scol + 8] = *(const int4*)&tmp[8];
        } else {
            const u16* src = z2 + 65536 + (mbase + srow) * 512 + (kb - 512) + scol;
            *(int4*)&smA[srow * 32 + scol]     = *(const int4*)(src);
            *(int4*)&smA[srow * 32 + scol + 8] = *(const int4*)(src + 8);
        }
        // stage B tile [128][32] from f32 w_ih [2048][1024]
        {
            const float* src = wih + (nbase + srow) * 1024 + kb + scol;
            alignas(16) u16 tmp[16];
            #pragma unroll
            for (int q = 0; q < 16; ++q) stbf(&tmp[q], src[q]);
            *(int4*)&smB[srow * 32 + scol]     = *(const int4*)&tmp[0];
            *(int4*)&smB[srow * 32 + scol + 8] = *(const int4*)&tmp[8];
        }
        __syncthreads();

        bf16x8 af[4], bfr[4];
        #pragma unroll
        for (int mi = 0; mi < 4; ++mi)
            af[mi] = *(const bf16x8*)&smA[(wm * 64 + mi * 16 + (lane & 15)) * 32 + (lane >> 4) * 8];
        #pragma unroll
        for (int ni = 0; ni < 4; ++ni)
            bfr[ni] = *(const bf16x8*)&smB[(wn * 64 + ni * 16 + (lane & 15)) * 32 + (lane >> 4) * 8];
        #pragma unroll
        for (int mi = 0; mi < 4; ++mi)
            #pragma unroll
            for (int ni = 0; ni < 4; ++ni)
                acc[mi][ni] = __builtin_amdgcn_mfma_f32_16x16x32_bf16(af[mi], bfr[ni], acc[mi][ni], 0, 0, 0);
        __syncthreads();
    }

    // epilogue: C/D layout col = lane&15, row = (lane>>4)*4 + r
    #pragma unroll
    for (int ni = 0; ni < 4; ++ni) {
        const size_t n = nbase + wn * 64 + ni * 16 + (lane & 15);
        const float bias = bih[n] + bhh[n];
        #pragma unroll
        for (int mi = 0; mi < 4; ++mi) {
            const size_t m0 = mbase + wm * 64 + mi * 16 + (lane >> 4) * 4;
            #pragma unroll
            for (int r = 0; r < 4; ++r)
                stbf(gates + (m0 + r) * 2048 + n, acc[mi][ni][r] + bias);
        }
    }
}

// ---------------------------------------------------------------------------
// One LSTM timestep (MFMA). Grid (32,4): j0 = bx*16, b0 = by*32.
// Block 256 = 4 waves; wave g computes gate group g (i,f,g,o).
// gates[b, g*512+j] = gx[b, g*512+j] + sum_k h_in[b,k] * w_hh[g*512+j, k]
// out_t is f32 (reference output dtype); h_out bf16 for next step's MFMA.
// ---------------------------------------------------------------------------
__global__ __launch_bounds__(256) void lstm_step(const u16* __restrict__ h_in,
                                                 float* __restrict__ c_state,
                                                 const u16* __restrict__ whh,
                                                 const u16* __restrict__ gx,
                                                 u16* __restrict__ h_out,
                                                 float* __restrict__ out_t) {
    __shared__ __align__(16) u16 smA[32 * 136];   // h tile [32 batch][128 k]
    __shared__ __align__(16) u16 smB[64 * 136];   // w tile [4 gates * 16 cols][128 k]
    __shared__ __align__(16) float smG[4 * 32 * 16];

    const int tid  = threadIdx.x;
    const int lane = tid & 63;
    const int wave = tid >> 6;          // gate group
    const int j0 = blockIdx.x * 16;
    const int b0 = blockIdx.y * 32;

    f32x4 acc[2] = {};

    for (int kt = 0; kt < 4; ++kt) {
        const int kb = kt * 128;
        // stage A: 32 rows x 128 cols
        {
            const int row = tid >> 3, col = (tid & 7) * 16;
            const u16* src = h_in + ((size_t)(b0 + row)) * 512 + kb + col;
            *(int4*)&smA[row * 136 + col]     = *(const int4*)(src);
            *(int4*)&smA[row * 136 + col + 8] = *(const int4*)(src + 8);
        }
        // stage B: 64 rows x 128 cols
        {
            const int row = tid >> 2, col = (tid & 3) * 32;
            const int g = row >> 4, n = row & 15;
            const u16* src = whh + ((size_t)(g * 512 + j0 + n)) * 512 + kb + col;
            #pragma unroll
            for (int q = 0; q < 4; ++q)
                *(int4*)&smB[row * 136 + col + q * 8] = *(const int4*)(src + q * 8);
        }
        __syncthreads();
        #pragma unroll
        for (int k2 = 0; k2 < 4; ++k2) {
            bf16x8 bfrag = *(const bf16x8*)&smB[(wave * 16 + (lane & 15)) * 136 + k2 * 32 + (lane >> 4) * 8];
            #pragma unroll
            for (int mi = 0; mi < 2; ++mi) {
                bf16x8 afrag = *(const bf16x8*)&smA[(mi * 16 + (lane & 15)) * 136 + k2 * 32 + (lane >> 4) * 8];
                acc[mi] = __builtin_amdgcn_mfma_f32_16x16x32_bf16(afrag, bfrag, acc[mi], 0, 0, 0);
            }
        }
        __syncthreads();
    }

    // dump gates to LDS: m = mi*16 + quad*4 + r (batch rel), n = lane&15 (j rel)
    #pragma unroll
    for (int mi = 0; mi < 2; ++mi)
        #pragma unroll
        for (int r = 0; r < 4; ++r) {
            const int m = mi * 16 + (lane >> 4) * 4 + r;
            smG[(wave * 32 + m) * 16 + (lane & 15)] = acc[mi][r];
        }
    __syncthreads();

    // elementwise LSTM: 512 elements, 2 per thread
    #pragma unroll
    for (int u = 0; u < 2; ++u) {
        const int e  = tid + u * 256;
        const int br = e >> 4, jr = e & 15;
        const size_t b = b0 + br;
        const size_t j = j0 + jr;
        const float gi = smG[(0 * 32 + br) * 16 + jr] + ldbf(gx + b * 2048 + 0    + j);
        const float gf = smG[(1 * 32 + br) * 16 + jr] + ldbf(gx + b * 2048 + 512  + j);
        const float gg = smG[(2 * 32 + br) * 16 + jr] + ldbf(gx + b * 2048 + 1024 + j);
        const float go = smG[(3 * 32 + br) * 16 + jr] + ldbf(gx + b * 2048 + 1536 + j);
        const float co = c_state[b * 512 + j];
        const float cn = sigm(gf) * co + sigm(gi) * tanhf(gg);
        const float hn = sigm(go) * tanhf(cn);
        c_state[b * 512 + j] = cn;
        stbf(h_out + b * 512 + j, hn);
        out_t[b * 512 + j] = hn;           // f32 output
    }
}

// ---------------------------------------------------------------------------
extern "C" void kernel_launch(void* const* d_in, const int* in_sizes, int n_in,
                              void* d_out, int out_size, void* d_ws, size_t ws_size,
                              hipStream_t stream) {
    const float* x   = (const float*)d_in[0];
    const float* z   = (const float*)d_in[1];
    const float* c0w = (const float*)d_in[2];
    const float* c0b = (const float*)d_in[3];
    const float* c1w = (const float*)d_in[4];
    const float* c1b = (const float*)d_in[5];
    const float* wih = (const float*)d_in[6];
    const float* whh = (const float*)d_in[7];
    const float* bih = (const float*)d_in[8];
    const float* bhh = (const float*)d_in[9];
    float* out = (float*)d_out;                // f32 output (reference dtype)
    char* ws = (char*)d_ws;

    // workspace layout (bytes) — total 371,195,904
    u16*   z1     = (u16*)(ws);                 //  33,554,432 B: [256][128][512] bf16
    u16*   z2     = (u16*)(ws + 33554432);      //  67,108,864 B: [512][128][512] bf16
    u16*   gates  = (u16*)(ws + 100663296);     // 267,911,168 B: [511][128][2048] bf16
    float* cst    = (float*)(ws + 368574464);   //     262,144 B: [128][512] f32
    u16*   h0     = (u16*)(ws + 368836608);     //     131,072 B: [128][512] bf16
    u16*   h1     = (u16*)(ws + 368967680);     //     131,072 B
    u16*   whh_bf = (u16*)(ws + 369098752);     //   2,097,152 B: [2048][512] bf16

    hipMemsetAsync(cst, 0, 262144, stream);
    hipMemsetAsync(h0, 0, 131072, stream);
    hipMemsetAsync(h1, 0, 131072, stream);

    // convert w_hh to bf16 (2048*512 = 1,048,576 elements)
    cvt_bf16<<<dim3(4096), 256, 0, stream>>>(whh, whh_bf, 1048576);

    // upsample x2
    upsample<true ><<<dim3(16777216 / 256), 256, 0, stream>>>(z,  c0w, c0b, z1, 128, 2);
    upsample<false><<<dim3(33554432 / 256), 256, 0, stream>>>(z1, c1w, c1b, z2, 256, 1);

    // gates_x = [x[:-1] | z2[1:]] @ w_ih^T + b_ih + b_hh
    gemm_gates<<<dim3(511, 16), 256, 0, stream>>>(x, z2, wih, bih, bhh, gates);

    // sequential recurrence: 511 steps
    u16* hb[2] = {h0, h1};
    for (int t = 0; t < 511; ++t) {
        lstm_step<<<dim3(32, 4), 256, 0, stream>>>(
            hb[t & 1], cst, whh_bf,
            gates + (size_t)t * 262144,
            hb[(t + 1) & 1],
            out + (size_t)t * 65536);
    }
}